// Round 1
// baseline (2173.132 us; speedup 1.0000x reference)
//
#include <hip/hip_runtime.h>
#include <math.h>

#define NPTS 65536
#define DIMD 256
#define KCB  4096

// d_out float32 offsets (reference tuple order, flattened)
#define O_ZQ   0
#define O_IDX  16777216
#define O_LOSS 16842752
#define O_PERP 16842753
#define O_CS   16842754
#define O_EMAW 16846850
#define O_W    17895426

// ---------------- ww[k] = sum_d w[k,d]^2 ----------------
__global__ void k_ww(const float* __restrict__ w, float* __restrict__ ww) {
    int lane = threadIdx.x & 63;
    int row  = blockIdx.x * 4 + (threadIdx.x >> 6);
    float4 v = ((const float4*)(w + (size_t)row * DIMD))[lane];
    float s = v.x * v.x + v.y * v.y + v.z * v.z + v.w * v.w;
    #pragma unroll
    for (int off = 32; off; off >>= 1) s += __shfl_down(s, off);
    if (lane == 0) ww[row] = s;
}

// ---------------- argmin + counts + dw scatter ----------------
// block: 128 rows x (all K), k-tiles of 256, D superchunks of 32 in LDS.
// 256 threads as 16x16: ty owns 8 rows {64h+4ty+c}, tx owns 16 ks {64jj+4tx+c}.
#define ZLD 132   // padded leading dim for z tile  (16B-aligned: 132*4=528=33*16)
#define WLD 260   // padded leading dim for w tile  (260*4=1040=65*16)

__launch_bounds__(256, 2)
__global__ void k_argmin(const float* __restrict__ z,
                         const float* __restrict__ w,
                         const float* __restrict__ wwg,
                         float* __restrict__ counts,   // d_out O_CS region (zeroed)
                         float* __restrict__ dw,       // d_out O_EMAW region (zeroed)
                         int*   __restrict__ idxi,     // ws
                         float* __restrict__ idxf) {   // d_out O_IDX
    __shared__ __align__(16) float zs [32 * ZLD];
    __shared__ __align__(16) float ws2[32 * WLD];
    __shared__ float wws[256];
    __shared__ float zzs[128];
    __shared__ int   bis[128];

    const int t  = threadIdx.x;
    const int tx = t & 15;
    const int ty = t >> 4;
    const int row0 = blockIdx.x * 128;

    // per-row sum of squares (wave per row, coalesced)
    {
        const int lane = t & 63;
        const int wv   = t >> 6;
        for (int i = 0; i < 32; ++i) {
            int r = wv * 32 + i;
            float4 v = ((const float4*)(z + (size_t)(row0 + r) * DIMD))[lane];
            float s = v.x*v.x + v.y*v.y + v.z*v.z + v.w*v.w;
            #pragma unroll
            for (int off = 32; off; off >>= 1) s += __shfl_down(s, off);
            if (lane == 0) zzs[r] = s;
        }
    }
    __syncthreads();

    float zzr[8];
    #pragma unroll
    for (int i = 0; i < 8; ++i)
        zzr[i] = zzs[(i >> 2) * 64 + ty * 4 + (i & 3)];

    float minv[8]; int mini[8];
    #pragma unroll
    for (int i = 0; i < 8; ++i) { minv[i] = 3.0e38f; mini[i] = 0; }

    for (int kt = 0; kt < KCB / 256; ++kt) {
        const int k0 = kt * 256;
        float acc[8][16];
        #pragma unroll
        for (int i = 0; i < 8; ++i)
            #pragma unroll
            for (int j = 0; j < 16; ++j) acc[i][j] = 0.0f;

        for (int sc = 0; sc < 8; ++sc) {
            __syncthreads();
            // stage z chunk: 128 rows x 32 d -> zs[d][row]
            #pragma unroll
            for (int i = 0; i < 4; ++i) {
                int f = t + i * 256;            // 0..1023
                int r = f >> 3, dg = f & 7;
                float4 v = *(const float4*)(z + (size_t)(row0 + r) * DIMD + sc * 32 + dg * 4);
                int b = dg * 4;
                zs[(b + 0) * ZLD + r] = v.x;
                zs[(b + 1) * ZLD + r] = v.y;
                zs[(b + 2) * ZLD + r] = v.z;
                zs[(b + 3) * ZLD + r] = v.w;
            }
            // stage w chunk: 256 k x 32 d -> ws2[d][k]
            #pragma unroll
            for (int i = 0; i < 8; ++i) {
                int f = t + i * 256;            // 0..2047
                int k = f >> 3, dg = f & 7;
                float4 v = *(const float4*)(w + (size_t)(k0 + k) * DIMD + sc * 32 + dg * 4);
                int b = dg * 4;
                ws2[(b + 0) * WLD + k] = v.x;
                ws2[(b + 1) * WLD + k] = v.y;
                ws2[(b + 2) * WLD + k] = v.z;
                ws2[(b + 3) * WLD + k] = v.w;
            }
            if (sc == 0) wws[t] = wwg[k0 + t];
            __syncthreads();

            #pragma unroll 8
            for (int dd = 0; dd < 32; ++dd) {
                const float* zrow = &zs[dd * ZLD];
                const float* wrow = &ws2[dd * WLD];
                float4 za0 = *(const float4*)(zrow + ty * 4);
                float4 za1 = *(const float4*)(zrow + 64 + ty * 4);
                float4 wb0 = *(const float4*)(wrow + tx * 4);
                float4 wb1 = *(const float4*)(wrow + 64 + tx * 4);
                float4 wb2 = *(const float4*)(wrow + 128 + tx * 4);
                float4 wb3 = *(const float4*)(wrow + 192 + tx * 4);
                float za[8]  = {za0.x, za0.y, za0.z, za0.w, za1.x, za1.y, za1.z, za1.w};
                float wb[16] = {wb0.x, wb0.y, wb0.z, wb0.w, wb1.x, wb1.y, wb1.z, wb1.w,
                                wb2.x, wb2.y, wb2.z, wb2.w, wb3.x, wb3.y, wb3.z, wb3.w};
                #pragma unroll
                for (int i = 0; i < 8; ++i)
                    #pragma unroll
                    for (int j = 0; j < 16; ++j)
                        acc[i][j] = fmaf(za[i], wb[j], acc[i][j]);
            }
        }
        // distances + running argmin; j ascends with k_local -> first-index ties
        #pragma unroll
        for (int j = 0; j < 16; ++j) {
            int kl = (j >> 2) * 64 + tx * 4 + (j & 3);
            float wwk = wws[kl];
            int kg = k0 + kl;
            #pragma unroll
            for (int i = 0; i < 8; ++i) {
                float dv = (zzr[i] + wwk) - 2.0f * acc[i][j];
                if (dv < minv[i]) { minv[i] = dv; mini[i] = kg; }
            }
        }
    }

    // cross-tx merge (tie-break: smaller index)
    __syncthreads();
    float2* mbuf = (float2*)zs;
    #pragma unroll
    for (int i = 0; i < 8; ++i) {
        int r = (i >> 2) * 64 + ty * 4 + (i & 3);
        mbuf[r * 16 + tx] = make_float2(minv[i], __int_as_float(mini[i]));
    }
    __syncthreads();
    if (t < 128) {
        float bv = 3.0e38f; int bidx = 0x7fffffff;
        #pragma unroll
        for (int s = 0; s < 16; ++s) {
            float2 e = mbuf[t * 16 + s];
            int ei = __float_as_int(e.y);
            if (e.x < bv || (e.x == bv && ei < bidx)) { bv = e.x; bidx = ei; }
        }
        bis[t] = bidx;
        idxi[row0 + t] = bidx;
        idxf[row0 + t] = (float)bidx;
        atomicAdd(&counts[bidx], 1.0f);
    }
    __syncthreads();
    // dw scatter: dw[idx[r], :] += z[r, :]
    for (int r = 0; r < 128; ++r) {
        int k = bis[r];
        float v = z[(size_t)(row0 + r) * DIMD + t];
        atomicAdd(&dw[(size_t)k * DIMD + t], v);
    }
}

// ---------------- cluster-size EMA + perplexity (one block, 1024 thr) ----------------
__global__ void k_cs(const float* __restrict__ ema_cs,
                     float* __restrict__ cs_io,    // in: counts, out: normalized cs
                     float* __restrict__ perp) {
    __shared__ float2 red[16];
    int t = threadIdx.x;
    float csd[4];
    float nl = 0.f, el = 0.f;
    #pragma unroll
    for (int i = 0; i < 4; ++i) {
        int k = t * 4 + i;
        float c  = cs_io[k];
        float cd = ema_cs[k] * 0.99f + 0.01f * c;
        csd[i] = cd;
        nl += cd;
        float p = c * (1.0f / 65536.0f);
        el += p * logf(p + 1e-10f);
    }
    #pragma unroll
    for (int off = 32; off; off >>= 1) { nl += __shfl_down(nl, off); el += __shfl_down(el, off); }
    if ((t & 63) == 0) red[t >> 6] = make_float2(nl, el);
    __syncthreads();
    if (t == 0) {
        float n = 0.f, e = 0.f;
        for (int i = 0; i < 16; ++i) { n += red[i].x; e += red[i].y; }
        red[0] = make_float2(n, e);
        perp[0] = expf(-e);
    }
    __syncthreads();
    float n = red[0].x;
    float scale = n / (n + 4096.0f * 1e-5f);
    #pragma unroll
    for (int i = 0; i < 4; ++i)
        cs_io[t * 4 + i] = (csd[i] + 1e-5f) * scale;
}

// ---------------- new_ema_w (in-place over dw) + new_weight ----------------
__global__ void k_emaw(const float* __restrict__ ema_w,
                       const float* __restrict__ cs,
                       float* __restrict__ emaw_io,  // in: dw, out: new_ema_w
                       float* __restrict__ wout) {
    int i = (blockIdx.x * 256 + threadIdx.x) * 4;
    int k = i >> 8;
    float4 dv = *(const float4*)(emaw_io + i);
    float4 ev = *(const float4*)(ema_w + i);
    float c = cs[k];
    float4 ne;
    ne.x = ev.x * 0.99f + 0.01f * dv.x;
    ne.y = ev.y * 0.99f + 0.01f * dv.y;
    ne.z = ev.z * 0.99f + 0.01f * dv.z;
    ne.w = ev.w * 0.99f + 0.01f * dv.w;
    *(float4*)(emaw_io + i) = ne;
    float4 nw = make_float4(ne.x / c, ne.y / c, ne.z / c, ne.w / c);
    *(float4*)(wout + i) = nw;
}

// ---------------- z_q gather + straight-through + loss partial ----------------
__global__ void k_zq(const float* __restrict__ z,
                     const float* __restrict__ wnew,
                     const int* __restrict__ idxi,
                     float* __restrict__ zq,
                     float* __restrict__ sqacc) {
    __shared__ float red[4];
    int i = (blockIdx.x * 256 + threadIdx.x) * 4;
    int n = i >> 8;
    int d = i & 255;
    int k = idxi[n];
    float4 wv = *(const float4*)(wnew + (k << 8) + d);
    float4 zv = *(const float4*)(z + i);
    float4 o;  // replicate z + (z_q - z) rounding
    o.x = zv.x + (wv.x - zv.x);
    o.y = zv.y + (wv.y - zv.y);
    o.z = zv.z + (wv.z - zv.z);
    o.w = zv.w + (wv.w - zv.w);
    *(float4*)(zq + i) = o;
    float dx = wv.x - zv.x, dy = wv.y - zv.y, dz = wv.z - zv.z, dw_ = wv.w - zv.w;
    float s = dx*dx + dy*dy + dz*dz + dw_*dw_;
    #pragma unroll
    for (int off = 32; off; off >>= 1) s += __shfl_down(s, off);
    int lane = threadIdx.x & 63;
    if (lane == 0) red[threadIdx.x >> 6] = s;
    __syncthreads();
    if (threadIdx.x == 0) atomicAdd(sqacc, red[0] + red[1] + red[2] + red[3]);
}

__global__ void k_final(const float* __restrict__ sqacc, float* __restrict__ loss) {
    loss[0] = 1.25f * sqacc[0] * (1.0f / 16777216.0f);
}

extern "C" void kernel_launch(void* const* d_in, const int* in_sizes, int n_in,
                              void* d_out, int out_size, void* d_ws, size_t ws_size,
                              hipStream_t stream) {
    const float* z      = (const float*)d_in[0];
    const float* weight = (const float*)d_in[1];
    const float* ema_w  = (const float*)d_in[2];
    const float* ema_cs = (const float*)d_in[3];
    float* out = (float*)d_out;
    float* ws  = (float*)d_ws;

    float* ww   = ws;                    // 4096
    float* scal = ws + 4096;             // 16
    int*   idxi = (int*)(ws + 8192);     // 65536 ints

    // zero accumulation regions (re-poisoned before every timed launch)
    hipMemsetAsync(out + O_CS,   0, (size_t)KCB * 4, stream);
    hipMemsetAsync(out + O_EMAW, 0, (size_t)KCB * DIMD * 4, stream);
    hipMemsetAsync(scal,         0, 16 * 4, stream);

    k_ww    <<<KCB / 4, 256, 0, stream>>>(weight, ww);
    k_argmin<<<NPTS / 128, 256, 0, stream>>>(z, weight, ww,
                                             out + O_CS, out + O_EMAW,
                                             idxi, out + O_IDX);
    k_cs    <<<1, 1024, 0, stream>>>(ema_cs, out + O_CS, out + O_PERP);
    k_emaw  <<<(KCB * DIMD) / 1024, 256, 0, stream>>>(ema_w, out + O_CS,
                                                      out + O_EMAW, out + O_W);
    k_zq    <<<(NPTS * DIMD) / 1024, 256, 0, stream>>>(z, out + O_W, idxi,
                                                       out + O_ZQ, scal);
    k_final <<<1, 1, 0, stream>>>(scal, out + O_LOSS);
}

// Round 3
// 2000.724 us; speedup vs baseline: 1.0862x; 1.0862x over previous
//
#include <hip/hip_runtime.h>
#include <math.h>

#define NPTS 65536
#define DIMD 256
#define KCB  4096

// d_out float32 offsets (reference tuple order, flattened)
#define O_ZQ   0
#define O_IDX  16777216
#define O_LOSS 16842752
#define O_PERP 16842753
#define O_CS   16842754
#define O_EMAW 16846850
#define O_W    17895426

typedef __attribute__((address_space(3))) void lds_void;
typedef const __attribute__((address_space(1))) void gbl_void;

__device__ __forceinline__ void dma16(const float* g, float* l) {
    __builtin_amdgcn_global_load_lds((gbl_void*)g, (lds_void*)l, 16, 0, 0);
}

// ---------------- transpose: src [M][256] -> dst [256][M] ----------------
__global__ void k_transpose(const float* __restrict__ src, float* __restrict__ dst,
                            int M, int tiles_m) {
    __shared__ float tile[64][65];
    int bm = blockIdx.x % tiles_m;
    int bd = blockIdx.x / tiles_m;
    int m0 = bm * 64, d0 = bd * 64;
    int t = threadIdx.x;
    int rr = t >> 4;
    int cc = (t & 15) * 4;
    #pragma unroll
    for (int i = 0; i < 4; ++i) {
        int r = rr + i * 16;
        float4 v = *(const float4*)(src + (size_t)(m0 + r) * DIMD + d0 + cc);
        tile[r][cc + 0] = v.x; tile[r][cc + 1] = v.y;
        tile[r][cc + 2] = v.z; tile[r][cc + 3] = v.w;
    }
    __syncthreads();
    #pragma unroll
    for (int i = 0; i < 4; ++i) {
        int dr = rr + i * 16;
        float4 v = make_float4(tile[cc + 0][dr], tile[cc + 1][dr],
                               tile[cc + 2][dr], tile[cc + 3][dr]);
        *(float4*)(dst + (size_t)(d0 + dr) * M + m0 + cc) = v;
    }
}

// ---------------- ww[k] = sum_d w[k,d]^2 ----------------
__global__ void k_ww(const float* __restrict__ w, float* __restrict__ ww) {
    int lane = threadIdx.x & 63;
    int row  = blockIdx.x * 4 + (threadIdx.x >> 6);
    float4 v = ((const float4*)(w + (size_t)row * DIMD))[lane];
    float s = v.x * v.x + v.y * v.y + v.z * v.z + v.w * v.w;
    #pragma unroll
    for (int off = 32; off; off >>= 1) s += __shfl_down(s, off);
    if (lane == 0) ww[row] = s;
}

// ---------------- argmin + counts + dw scatter ----------------
// 512 blocks x 256 thr. Block: 128 rows x all K; k-tiles of 256; d-chunks of 32.
// Staging is pure global_load_lds DMA from pre-transposed zT/wT.
// DMA layout law: lane l writes LDS at (wave-uniform base) + l*16B. So per
// round: z -> f=r*256+t, d=f>>5, col4=f&31, base=zs+r*1024+wv*256;
//        w -> f=r*256+t, d=r*4+wv (one wave per 256-float k-row), base likewise.
__launch_bounds__(256, 2)
__global__ void k_argmin(const float* __restrict__ z,    // [N][D] original
                         const float* __restrict__ zT,   // [D][N]
                         const float* __restrict__ wT,   // [D][K]
                         const float* __restrict__ wwg,
                         float* __restrict__ counts,
                         float* __restrict__ dw,
                         int*   __restrict__ idxi,
                         float* __restrict__ idxf) {
    __shared__ __align__(16) float zs [32 * 128];   // 16 KB  [d][row]
    __shared__ __align__(16) float ws2[32 * 256];   // 32 KB  [d][k]
    __shared__ float zzs[128];
    __shared__ int   bis[128];

    const int t    = threadIdx.x;
    const int tx   = t & 15;
    const int ty   = t >> 4;
    const int wv   = t >> 6;
    const int row0 = blockIdx.x * 128;

    // per-row sum of squares (wave per row, coalesced)
    {
        const int lane = t & 63;
        for (int i = 0; i < 32; ++i) {
            int r = wv * 32 + i;
            float4 v = ((const float4*)(z + (size_t)(row0 + r) * DIMD))[lane];
            float s = v.x*v.x + v.y*v.y + v.z*v.z + v.w*v.w;
            #pragma unroll
            for (int off = 32; off; off >>= 1) s += __shfl_down(s, off);
            if (lane == 0) zzs[r] = s;
        }
    }
    __syncthreads();

    float zzr[8];
    #pragma unroll
    for (int i = 0; i < 8; ++i)
        zzr[i] = zzs[(i >> 2) * 64 + ty * 4 + (i & 3)];

    float minv[8]; int mini[8];
    #pragma unroll
    for (int i = 0; i < 8; ++i) { minv[i] = 3.0e38f; mini[i] = 0; }

    for (int kt = 0; kt < KCB / 256; ++kt) {
        const int k0 = kt * 256;
        float acc[8][16];
        #pragma unroll
        for (int i = 0; i < 8; ++i)
            #pragma unroll
            for (int j = 0; j < 16; ++j) acc[i][j] = 0.0f;

        for (int sc = 0; sc < 8; ++sc) {
            __syncthreads();   // previous chunk's LDS reads complete
            // z chunk DMA: 32 d x 128 rows = 4096 floats, 4 rounds x 1024 floats
            #pragma unroll
            for (int r = 0; r < 4; ++r) {
                int f = r * 256 + t;
                const float* g = zT + (size_t)(sc * 32 + (f >> 5)) * NPTS
                               + row0 + (f & 31) * 4;
                dma16(g, zs + r * 1024 + wv * 256);
            }
            // w chunk DMA: 32 d x 256 k = 8192 floats, 8 rounds x 1024 floats
            #pragma unroll
            for (int r = 0; r < 8; ++r) {
                int f = r * 256 + t;
                const float* g = wT + (size_t)(sc * 32 + (f >> 6)) * KCB
                               + k0 + (f & 63) * 4;
                dma16(g, ws2 + r * 1024 + wv * 256);
            }
            __syncthreads();   // vmcnt(0) drain -> chunk ready

            #pragma unroll 8
            for (int dd = 0; dd < 32; ++dd) {
                const float* zrow = zs  + dd * 128;
                const float* wrow = ws2 + dd * 256;
                float4 za0 = *(const float4*)(zrow + ty * 4);
                float4 za1 = *(const float4*)(zrow + 64 + ty * 4);
                float4 wb0 = *(const float4*)(wrow + tx * 4);
                float4 wb1 = *(const float4*)(wrow + 64 + tx * 4);
                float4 wb2 = *(const float4*)(wrow + 128 + tx * 4);
                float4 wb3 = *(const float4*)(wrow + 192 + tx * 4);
                float za[8]  = {za0.x, za0.y, za0.z, za0.w, za1.x, za1.y, za1.z, za1.w};
                float wb[16] = {wb0.x, wb0.y, wb0.z, wb0.w, wb1.x, wb1.y, wb1.z, wb1.w,
                                wb2.x, wb2.y, wb2.z, wb2.w, wb3.x, wb3.y, wb3.z, wb3.w};
                #pragma unroll
                for (int i = 0; i < 8; ++i)
                    #pragma unroll
                    for (int j = 0; j < 16; ++j)
                        acc[i][j] = fmaf(za[i], wb[j], acc[i][j]);
            }
        }
        // distances + running argmin; ascending k -> first-index tie-break
        #pragma unroll
        for (int j = 0; j < 16; ++j) {
            int kl = (j >> 2) * 64 + tx * 4 + (j & 3);
            float wwk = wwg[k0 + kl];    // 16 KB, L1/L2-resident
            int kg = k0 + kl;
            #pragma unroll
            for (int i = 0; i < 8; ++i) {
                float dv = (zzr[i] + wwk) - 2.0f * acc[i][j];
                if (dv < minv[i]) { minv[i] = dv; mini[i] = kg; }
            }
        }
    }

    // cross-tx merge (tie-break: smaller index)
    __syncthreads();
    float2* mbuf = (float2*)zs;
    #pragma unroll
    for (int i = 0; i < 8; ++i) {
        int r = (i >> 2) * 64 + ty * 4 + (i & 3);
        mbuf[r * 16 + tx] = make_float2(minv[i], __int_as_float(mini[i]));
    }
    __syncthreads();
    if (t < 128) {
        float bv = 3.0e38f; int bidx = 0x7fffffff;
        #pragma unroll
        for (int s = 0; s < 16; ++s) {
            float2 e = mbuf[t * 16 + s];
            int ei = __float_as_int(e.y);
            if (e.x < bv || (e.x == bv && ei < bidx)) { bv = e.x; bidx = ei; }
        }
        bis[t] = bidx;
        idxi[row0 + t] = bidx;
        idxf[row0 + t] = (float)bidx;
        atomicAdd(&counts[bidx], 1.0f);
    }
    __syncthreads();
    // dw scatter: dw[idx[r], :] += z[r, :]
    for (int r = 0; r < 128; ++r) {
        int k = bis[r];
        float v = z[(size_t)(row0 + r) * DIMD + t];
        atomicAdd(&dw[(size_t)k * DIMD + t], v);
    }
}

// ---------------- cluster-size EMA + perplexity ----------------
__global__ void k_cs(const float* __restrict__ ema_cs,
                     float* __restrict__ cs_io,
                     float* __restrict__ perp) {
    __shared__ float2 red[16];
    int t = threadIdx.x;
    float csd[4];
    float nl = 0.f, el = 0.f;
    #pragma unroll
    for (int i = 0; i < 4; ++i) {
        int k = t * 4 + i;
        float c  = cs_io[k];
        float cd = ema_cs[k] * 0.99f + 0.01f * c;
        csd[i] = cd;
        nl += cd;
        float p = c * (1.0f / 65536.0f);
        el += p * logf(p + 1e-10f);
    }
    #pragma unroll
    for (int off = 32; off; off >>= 1) { nl += __shfl_down(nl, off); el += __shfl_down(el, off); }
    if ((t & 63) == 0) red[t >> 6] = make_float2(nl, el);
    __syncthreads();
    if (t == 0) {
        float n = 0.f, e = 0.f;
        for (int i = 0; i < 16; ++i) { n += red[i].x; e += red[i].y; }
        red[0] = make_float2(n, e);
        perp[0] = expf(-e);
    }
    __syncthreads();
    float n = red[0].x;
    float scale = n / (n + 4096.0f * 1e-5f);
    #pragma unroll
    for (int i = 0; i < 4; ++i)
        cs_io[t * 4 + i] = (csd[i] + 1e-5f) * scale;
}

// ---------------- new_ema_w (in-place over dw) + new_weight ----------------
__global__ void k_emaw(const float* __restrict__ ema_w,
                       const float* __restrict__ cs,
                       float* __restrict__ emaw_io,
                       float* __restrict__ wout) {
    int i = (blockIdx.x * 256 + threadIdx.x) * 4;
    int k = i >> 8;
    float4 dv = *(const float4*)(emaw_io + i);
    float4 ev = *(const float4*)(ema_w + i);
    float c = cs[k];
    float4 ne;
    ne.x = ev.x * 0.99f + 0.01f * dv.x;
    ne.y = ev.y * 0.99f + 0.01f * dv.y;
    ne.z = ev.z * 0.99f + 0.01f * dv.z;
    ne.w = ev.w * 0.99f + 0.01f * dv.w;
    *(float4*)(emaw_io + i) = ne;
    float4 nw = make_float4(ne.x / c, ne.y / c, ne.z / c, ne.w / c);
    *(float4*)(wout + i) = nw;
}

// ---------------- z_q gather + straight-through + loss partial ----------------
__global__ void k_zq(const float* __restrict__ z,
                     const float* __restrict__ wnew,
                     const int* __restrict__ idxi,
                     float* __restrict__ zq,
                     float* __restrict__ sqacc) {
    __shared__ float red[4];
    int i = (blockIdx.x * 256 + threadIdx.x) * 4;
    int n = i >> 8;
    int d = i & 255;
    int k = idxi[n];
    float4 wv = *(const float4*)(wnew + (k << 8) + d);
    float4 zv = *(const float4*)(z + i);
    float4 o;
    o.x = zv.x + (wv.x - zv.x);
    o.y = zv.y + (wv.y - zv.y);
    o.z = zv.z + (wv.z - zv.z);
    o.w = zv.w + (wv.w - zv.w);
    *(float4*)(zq + i) = o;
    float dx = wv.x - zv.x, dy = wv.y - zv.y, dz = wv.z - zv.z, dw_ = wv.w - zv.w;
    float s = dx*dx + dy*dy + dz*dz + dw_*dw_;
    #pragma unroll
    for (int off = 32; off; off >>= 1) s += __shfl_down(s, off);
    int lane = threadIdx.x & 63;
    if (lane == 0) red[threadIdx.x >> 6] = s;
    __syncthreads();
    if (threadIdx.x == 0) atomicAdd(sqacc, red[0] + red[1] + red[2] + red[3]);
}

__global__ void k_final(const float* __restrict__ sqacc, float* __restrict__ loss) {
    loss[0] = 1.25f * sqacc[0] * (1.0f / 16777216.0f);
}

extern "C" void kernel_launch(void* const* d_in, const int* in_sizes, int n_in,
                              void* d_out, int out_size, void* d_ws, size_t ws_size,
                              hipStream_t stream) {
    const float* z      = (const float*)d_in[0];
    const float* weight = (const float*)d_in[1];
    const float* ema_w  = (const float*)d_in[2];
    const float* ema_cs = (const float*)d_in[3];
    float* out = (float*)d_out;
    float* ws  = (float*)d_ws;

    float* ww   = ws;                    // 4096
    float* scal = ws + 4096;             // 16
    int*   idxi = (int*)(ws + 8192);     // 65536 ints

    float* zT = out + O_ZQ;   // scratch until k_zq overwrites (stream-ordered)
    float* wT = out + O_W;    // scratch until k_emaw overwrites

    hipMemsetAsync(out + O_CS,   0, (size_t)KCB * 4, stream);
    hipMemsetAsync(out + O_EMAW, 0, (size_t)KCB * DIMD * 4, stream);
    hipMemsetAsync(scal,         0, 16 * 4, stream);

    k_transpose<<<(NPTS / 64) * 4, 256, 0, stream>>>(z,      zT, NPTS, NPTS / 64);
    k_transpose<<<(KCB  / 64) * 4, 256, 0, stream>>>(weight, wT, KCB,  KCB  / 64);
    k_ww       <<<KCB / 4, 256, 0, stream>>>(weight, ww);
    k_argmin   <<<NPTS / 128, 256, 0, stream>>>(z, zT, wT, ww,
                                                out + O_CS, out + O_EMAW,
                                                idxi, out + O_IDX);
    k_cs       <<<1, 1024, 0, stream>>>(ema_cs, out + O_CS, out + O_PERP);
    k_emaw     <<<(KCB * DIMD) / 1024, 256, 0, stream>>>(ema_w, out + O_CS,
                                                         out + O_EMAW, out + O_W);
    k_zq       <<<(NPTS * DIMD) / 1024, 256, 0, stream>>>(z, out + O_W, idxi,
                                                          out + O_ZQ, scal);
    k_final    <<<1, 1, 0, stream>>>(scal, out + O_LOSS);
}

// Round 4
// 919.804 us; speedup vs baseline: 2.3626x; 2.1752x over previous
//
#include <hip/hip_runtime.h>
#include <math.h>

#define NPTS 65536
#define DIMD 256
#define KCB  4096
#define MARGIN 2.0f

// d_out float32 offsets (reference tuple order, flattened)
#define O_ZQ   0
#define O_IDX  16777216
#define O_LOSS 16842752
#define O_PERP 16842753
#define O_CS   16842754
#define O_EMAW 16846850
#define O_W    17895426

// scratch layout inside d_out O_ZQ region (67.1 MB; dead until k_zq):
//   zbf16  : float-offset 0         (32 MB = 8,388,608 floats)
//   wbf16  : float-offset 8,388,608 (2 MB)
//   cand   : float-offset 8,912,896 (65536 x 17 ints = 4.46 MB)
#define OFF_WBF  8388608
#define OFF_CAND 8912896

typedef __attribute__((address_space(3))) void lds_void;
typedef const __attribute__((address_space(1))) void gbl_void;
typedef __attribute__((ext_vector_type(8))) short short8;   // 8 bf16 (4 VGPRs)
typedef __attribute__((ext_vector_type(4))) float f32x4;

__device__ __forceinline__ void dma16(const void* g, void* l) {
    __builtin_amdgcn_global_load_lds((gbl_void*)g, (lds_void*)l, 16, 0, 0);
}
__device__ __forceinline__ unsigned short f2bf(float f) {   // RNE
    unsigned u = __float_as_uint(f);
    return (unsigned short)((u + 0x7FFF + ((u >> 16) & 1)) >> 16);
}

// ---------------- fp32 -> bf16 pack + row sum-of-squares ----------------
// wave per row (64 lanes x 4 floats = 256).
__global__ void k_prep(const float* __restrict__ src, unsigned* __restrict__ dst,
                       float* __restrict__ ss) {
    int l   = threadIdx.x & 63;
    int row = blockIdx.x * 4 + (threadIdx.x >> 6);
    float4 v = ((const float4*)(src + (size_t)row * DIMD))[l];
    unsigned b0 = f2bf(v.x), b1 = f2bf(v.y), b2 = f2bf(v.z), b3 = f2bf(v.w);
    uint2 pk = make_uint2(b0 | (b1 << 16), b2 | (b3 << 16));
    ((uint2*)dst)[(size_t)row * 64 + l] = pk;
    float s = v.x*v.x + v.y*v.y + v.z*v.z + v.w*v.w;
    #pragma unroll
    for (int off = 32; off; off >>= 1) s += __shfl_down(s, off);
    if (l == 0) ss[row] = s;
}

// ---------------- coarse bf16 MFMA argmin, 2-sweep + margin lists ----------
// 512 blocks x 256 thr (4 waves x 32 rows = 128 rows/block), all K per block.
// k-tiles of 16 codes; w-tile LDS layout: entry e = (c*4+q)*16 + n16 (16 B),
// so per-chunk ds_read is contiguous 1 KB/wave; staging is per-lane-gather DMA.
__launch_bounds__(256)
__global__ void k_coarse(const unsigned* __restrict__ zbf,   // [N][256] bf16
                         const unsigned* __restrict__ wbf,   // [K][256] bf16
                         const float* __restrict__ wwg,
                         int* __restrict__ cand) {           // [N][17]
    __shared__ uint4 wtile[2][512];        // 16 KB double buffer
    __shared__ int   cnt[128];
    __shared__ int   ids[128][16];

    const int t    = threadIdx.x;
    const int wv   = t >> 6;
    const int l    = t & 63;
    const int q    = l >> 4;
    const int n16  = l & 15;
    const int row0 = blockIdx.x * 128;
    const char* wb = (const char*)wbf;

    // A-frags: 2 sets x 8 chunks, register-resident for the whole kernel
    union { uint4 u; short8 s; } afr[2][8];
    #pragma unroll
    for (int s = 0; s < 2; ++s) {
        int row = row0 + wv * 32 + s * 16 + n16;
        const char* zb = (const char*)zbf + ((size_t)row << 9) + q * 16;
        #pragma unroll
        for (int c = 0; c < 8; ++c)
            afr[s][c].u = *(const uint4*)(zb + c * 64);
    }

    float minv[8], gmin[8];
    #pragma unroll
    for (int i = 0; i < 8; ++i) minv[i] = 3.0e38f;

    for (int pass = 0; pass < 2; ++pass) {
        if (pass == 1) {            // init candidate lists
            if (t < 128) cnt[t] = 0;
        }
        // stage tile 0 into buf 0 (2 DMA rounds per wave)
        #pragma unroll
        for (int i = 0; i < 2; ++i) {
            int r = wv * 2 + i;
            const char* g = wb + ((size_t)(n16) << 9) + (4 * r + q) * 16;
            dma16(g, (char*)&wtile[0][r * 64]);
        }
        __syncthreads();

        for (int kt = 0; kt < KCB / 16; ++kt) {
            const int k0  = kt * 16;
            const int cur = kt & 1;
            if (kt + 1 < KCB / 16) {   // prefetch next tile into other buffer
                #pragma unroll
                for (int i = 0; i < 2; ++i) {
                    int r = wv * 2 + i;
                    const char* g = wb + ((size_t)(k0 + 16 + n16) << 9)
                                  + (4 * r + q) * 16;
                    dma16(g, (char*)&wtile[cur ^ 1][r * 64]);
                }
            }
            f32x4 acc0 = {0.f, 0.f, 0.f, 0.f};
            f32x4 acc1 = {0.f, 0.f, 0.f, 0.f};
            const uint4* wt = &wtile[cur][0];
            #pragma unroll
            for (int c = 0; c < 8; ++c) {
                union { uint4 u; short8 s; } bf;
                bf.u = wt[c * 64 + l];
                acc0 = __builtin_amdgcn_mfma_f32_16x16x32_bf16(afr[0][c].s, bf.s, acc0, 0, 0, 0);
                acc1 = __builtin_amdgcn_mfma_f32_16x16x32_bf16(afr[1][c].s, bf.s, acc1, 0, 0, 0);
            }
            float wwv = wwg[k0 + n16];
            if (pass == 0) {
                #pragma unroll
                for (int r = 0; r < 4; ++r) {
                    minv[r]     = fminf(minv[r],     fmaf(-2.f, acc0[r], wwv));
                    minv[4 + r] = fminf(minv[4 + r], fmaf(-2.f, acc1[r], wwv));
                }
            } else {
                #pragma unroll
                for (int r = 0; r < 8; ++r) {
                    float core = fmaf(-2.f, (r < 4 ? acc0[r & 3] : acc1[r & 3]), wwv);
                    if (core <= gmin[r] + MARGIN) {
                        int row_l = wv * 32 + (r >> 2) * 16 + q * 4 + (r & 3);
                        int pos = atomicAdd(&cnt[row_l], 1);
                        if (pos < 16) ids[row_l][pos] = k0 + n16;
                    }
                }
            }
            __syncthreads();
        }
        if (pass == 0) {   // butterfly min across the 16 lanes of each quad
            #pragma unroll
            for (int i = 0; i < 8; ++i) {
                float m = minv[i];
                #pragma unroll
                for (int msk = 1; msk < 16; msk <<= 1)
                    m = fminf(m, __shfl_xor(m, msk));
                gmin[i] = m;
            }
        }
    }
    // flush lists
    if (t < 128) {
        int n = cnt[t]; if (n > 16) n = 16;
        int* dst = cand + (size_t)(row0 + t) * 17;
        dst[0] = n;
        for (int j = 0; j < n; ++j) dst[1 + j] = ids[t][j];
    }
}

// ---------------- fp32 rescore of candidates ----------------
// wave per row; exact formula (zz + ww) - 2*dot, first-index tie-break.
__global__ void k_refine(const float* __restrict__ z,
                         const float* __restrict__ w,
                         const float* __restrict__ zz,
                         const float* __restrict__ wwg,
                         const int* __restrict__ cand,
                         float* __restrict__ counts,
                         int*   __restrict__ idxi,
                         float* __restrict__ idxf) {
    int l   = threadIdx.x & 63;
    int row = blockIdx.x * 4 + (threadIdx.x >> 6);
    const int* cl = cand + (size_t)row * 17;
    int n = cl[0];
    float4 zv = ((const float4*)(z + (size_t)row * DIMD))[l];
    float zzv = zz[row];
    float bd = 3.0e38f; int bi = 0x7fffffff;
    for (int j = 0; j < n; ++j) {
        int k = cl[1 + j];
        float4 wv = ((const float4*)(w + (size_t)k * DIMD))[l];
        float s = zv.x*wv.x + zv.y*wv.y + zv.z*wv.z + zv.w*wv.w;
        #pragma unroll
        for (int off = 32; off; off >>= 1) s += __shfl_xor(s, off);
        float d = (zzv + wwg[k]) - 2.0f * s;
        if (d < bd || (d == bd && k < bi)) { bd = d; bi = k; }
    }
    if (l == 0) {
        idxi[row] = bi;
        idxf[row] = (float)bi;
        atomicAdd(&counts[bi], 1.0f);
    }
}

// ---------------- dw scatter: dw[idx[r],:] += z[r,:] ----------------
__global__ void k_scatter(const float* __restrict__ z,
                          const int* __restrict__ idxi,
                          float* __restrict__ dw) {
    int t = threadIdx.x;
    int row0 = blockIdx.x * 128;
    for (int r = 0; r < 128; ++r) {
        int k = idxi[row0 + r];
        float v = z[(size_t)(row0 + r) * DIMD + t];
        atomicAdd(&dw[(size_t)k * DIMD + t], v);
    }
}

// ---------------- cluster-size EMA + perplexity ----------------
__global__ void k_cs(const float* __restrict__ ema_cs,
                     float* __restrict__ cs_io,
                     float* __restrict__ perp) {
    __shared__ float2 red[16];
    int t = threadIdx.x;
    float csd[4];
    float nl = 0.f, el = 0.f;
    #pragma unroll
    for (int i = 0; i < 4; ++i) {
        int k = t * 4 + i;
        float c  = cs_io[k];
        float cd = ema_cs[k] * 0.99f + 0.01f * c;
        csd[i] = cd;
        nl += cd;
        float p = c * (1.0f / 65536.0f);
        el += p * logf(p + 1e-10f);
    }
    #pragma unroll
    for (int off = 32; off; off >>= 1) { nl += __shfl_down(nl, off); el += __shfl_down(el, off); }
    if ((t & 63) == 0) red[t >> 6] = make_float2(nl, el);
    __syncthreads();
    if (t == 0) {
        float n = 0.f, e = 0.f;
        for (int i = 0; i < 16; ++i) { n += red[i].x; e += red[i].y; }
        red[0] = make_float2(n, e);
        perp[0] = expf(-e);
    }
    __syncthreads();
    float n = red[0].x;
    float scale = n / (n + 4096.0f * 1e-5f);
    #pragma unroll
    for (int i = 0; i < 4; ++i)
        cs_io[t * 4 + i] = (csd[i] + 1e-5f) * scale;
}

// ---------------- new_ema_w (in-place over dw) + new_weight ----------------
__global__ void k_emaw(const float* __restrict__ ema_w,
                       const float* __restrict__ cs,
                       float* __restrict__ emaw_io,
                       float* __restrict__ wout) {
    int i = (blockIdx.x * 256 + threadIdx.x) * 4;
    int k = i >> 8;
    float4 dv = *(const float4*)(emaw_io + i);
    float4 ev = *(const float4*)(ema_w + i);
    float c = cs[k];
    float4 ne;
    ne.x = ev.x * 0.99f + 0.01f * dv.x;
    ne.y = ev.y * 0.99f + 0.01f * dv.y;
    ne.z = ev.z * 0.99f + 0.01f * dv.z;
    ne.w = ev.w * 0.99f + 0.01f * dv.w;
    *(float4*)(emaw_io + i) = ne;
    float4 nw = make_float4(ne.x / c, ne.y / c, ne.z / c, ne.w / c);
    *(float4*)(wout + i) = nw;
}

// ---------------- z_q gather + straight-through + loss partial ----------------
__global__ void k_zq(const float* __restrict__ z,
                     const float* __restrict__ wnew,
                     const int* __restrict__ idxi,
                     float* __restrict__ zq,
                     float* __restrict__ sqacc) {
    __shared__ float red[4];
    int i = (blockIdx.x * 256 + threadIdx.x) * 4;
    int n = i >> 8;
    int d = i & 255;
    int k = idxi[n];
    float4 wv = *(const float4*)(wnew + (k << 8) + d);
    float4 zv = *(const float4*)(z + i);
    float4 o;
    o.x = zv.x + (wv.x - zv.x);
    o.y = zv.y + (wv.y - zv.y);
    o.z = zv.z + (wv.z - zv.z);
    o.w = zv.w + (wv.w - zv.w);
    *(float4*)(zq + i) = o;
    float dx = wv.x - zv.x, dy = wv.y - zv.y, dz = wv.z - zv.z, dw_ = wv.w - zv.w;
    float s = dx*dx + dy*dy + dz*dz + dw_*dw_;
    #pragma unroll
    for (int off = 32; off; off >>= 1) s += __shfl_down(s, off);
    int lane = threadIdx.x & 63;
    if (lane == 0) red[threadIdx.x >> 6] = s;
    __syncthreads();
    if (threadIdx.x == 0) atomicAdd(sqacc, red[0] + red[1] + red[2] + red[3]);
}

__global__ void k_final(const float* __restrict__ sqacc, float* __restrict__ loss) {
    loss[0] = 1.25f * sqacc[0] * (1.0f / 16777216.0f);
}

extern "C" void kernel_launch(void* const* d_in, const int* in_sizes, int n_in,
                              void* d_out, int out_size, void* d_ws, size_t ws_size,
                              hipStream_t stream) {
    const float* z      = (const float*)d_in[0];
    const float* weight = (const float*)d_in[1];
    const float* ema_w  = (const float*)d_in[2];
    const float* ema_cs = (const float*)d_in[3];
    float* out = (float*)d_out;
    float* ws  = (float*)d_ws;

    float* scal = ws + 4096;             // 16
    int*   idxi = (int*)(ws + 8192);     // 65536 ints

    unsigned* zbf  = (unsigned*)(out + O_ZQ);
    unsigned* wbf  = (unsigned*)(out + O_ZQ + OFF_WBF);
    int*      cand = (int*)(out + O_ZQ + OFF_CAND);
    float*    zz   = out + O_EMAW;             // first 64K floats of EMAW region
    float*    wwg  = out + O_EMAW + NPTS >= out + O_EMAW ? out + O_EMAW + 65536 : out; // zz[65536], ww[4096]

    hipMemsetAsync(scal,       0, 16 * 4, stream);
    hipMemsetAsync(out + O_CS, 0, (size_t)KCB * 4, stream);

    k_prep   <<<NPTS / 4, 256, 0, stream>>>(z, zbf, zz);
    k_prep   <<<KCB  / 4, 256, 0, stream>>>(weight, wbf, wwg);
    k_coarse <<<NPTS / 128, 256, 0, stream>>>(zbf, wbf, wwg, cand);
    k_refine <<<NPTS / 4, 256, 0, stream>>>(z, weight, zz, wwg, cand,
                                            out + O_CS, idxi, out + O_IDX);
    // zz/wwg dead now; zero the EMAW accumulator region
    hipMemsetAsync(out + O_EMAW, 0, (size_t)KCB * DIMD * 4, stream);
    k_scatter<<<NPTS / 128, 256, 0, stream>>>(z, idxi, out + O_EMAW);
    k_cs     <<<1, 1024, 0, stream>>>(ema_cs, out + O_CS, out + O_PERP);
    k_emaw   <<<(KCB * DIMD) / 1024, 256, 0, stream>>>(ema_w, out + O_CS,
                                                       out + O_EMAW, out + O_W);
    k_zq     <<<(NPTS * DIMD) / 1024, 256, 0, stream>>>(z, out + O_W, idxi,
                                                        out + O_ZQ, scal);
    k_final  <<<1, 1, 0, stream>>>(scal, out + O_LOSS);
}